// Round 1
// baseline (259.649 us; speedup 1.0000x reference)
//
#include <hip/hip_runtime.h>

#define NN   17
#define DIN  64
#define DOUT 64
#define GRP  4            // (b,t) positions per block per iteration
#define NBT  (128*300)    // 38400
#define XS_F (GRP*NN*DIN) // 4352 floats staged per group
#define XS_V (XS_F/4)     // 1088 float4
#define NLD  5            // ceil(1088/256)

__global__ __launch_bounds__(256, 2) void gcn_fp32_kernel(
    const float* __restrict__ x, const float* __restrict__ W,
    const float* __restrict__ M, const float* __restrict__ adj2,
    const float* __restrict__ bias, const float* __restrict__ adj,
    float* __restrict__ out, int nGroups, int gridBlocks)
{
    __shared__ float xs[XS_F];        // 17408 B
    __shared__ float aoff[NN][NN];    // symmetrized off-diagonal
    __shared__ float adiag[NN];

    const int tid  = threadIdx.x;
    const int lane = tid & 63;
    const int wv   = tid >> 6;

    // Symmetrized adjacency: a_sym = 0.5*((adj+adj2) + (adj+adj2)^T)
    for (int t = tid; t < NN*NN; t += 256) {
        int n = t / NN, m = t % NN;
        float v = 0.5f * ((adj[n*NN+m] + adj2[n*NN+m]) + (adj[m*NN+n] + adj2[m*NN+n]));
        aoff[n][m] = (n == m) ? 0.0f : v;
        if (n == m) adiag[n] = v;
    }

    // Per-lane weight columns in registers (amortized over grid-stride loop)
    float w0[DIN], w1[DIN];
    #pragma unroll
    for (int i = 0; i < DIN; ++i) {
        w0[i] = W[i*DOUT + lane];
        w1[i] = W[DIN*DOUT + i*DOUT + lane];
    }
    float Mreg[NN];
    #pragma unroll
    for (int m = 0; m < NN; ++m) Mreg[m] = M[m*DOUT + lane];
    const float bo = bias[lane];

    float4 stg[NLD];
    int g = blockIdx.x;
    // Prologue: load first group into regs
    {
        const float4* src = (const float4*)(x + (size_t)g * XS_F);
        #pragma unroll
        for (int k = 0; k < NLD; ++k) {
            int idx = tid + k*256;
            if (idx < XS_V) stg[k] = src[idx];
        }
    }

    for (; g < nGroups; g += gridBlocks) {
        __syncthreads();                       // LDS free from previous iter (+ aoff ready)
        float4* dst4 = (float4*)xs;
        #pragma unroll
        for (int k = 0; k < NLD; ++k) {
            int idx = tid + k*256;
            if (idx < XS_V) dst4[idx] = stg[k];
        }
        __syncthreads();

        // Issue next group's global loads early (hide HBM latency under compute)
        int gn = g + gridBlocks;
        if (gn < nGroups) {
            const float4* src = (const float4*)(x + (size_t)gn * XS_F);
            #pragma unroll
            for (int k = 0; k < NLD; ++k) {
                int idx = tid + k*256;
                if (idx < XS_V) stg[k] = src[idx];
            }
        }

        // Compute: wave wv handles bt = g*GRP + wv; lane = output column
        const float* xw = xs + wv * NN * DIN;
        float h0[NN], h1[NN];
        #pragma unroll
        for (int m = 0; m < NN; ++m) { h0[m] = 0.f; h1[m] = 0.f; }

        #pragma unroll
        for (int m = 0; m < NN; ++m) {
            const float4* xr = (const float4*)(xw + m*DIN);
            #pragma unroll
            for (int i4 = 0; i4 < DIN/4; ++i4) {
                float4 v = xr[i4];               // wave-uniform LDS broadcast
                h0[m] = fmaf(v.x, w0[i4*4+0], h0[m]);
                h0[m] = fmaf(v.y, w0[i4*4+1], h0[m]);
                h0[m] = fmaf(v.z, w0[i4*4+2], h0[m]);
                h0[m] = fmaf(v.w, w0[i4*4+3], h0[m]);
                h1[m] = fmaf(v.x, w1[i4*4+0], h1[m]);
                h1[m] = fmaf(v.y, w1[i4*4+1], h1[m]);
                h1[m] = fmaf(v.z, w1[i4*4+2], h1[m]);
                h1[m] = fmaf(v.w, w1[i4*4+3], h1[m]);
            }
        }

        // Mixing: out[n,o] = diag[n]*M[n,o]*h0[n] + sum_m aoff[n,m]*M[m,o]*h1[m]
        #pragma unroll
        for (int m = 0; m < NN; ++m) h1[m] *= Mreg[m];

        size_t bt = (size_t)g * GRP + wv;
        float* orow = out + bt * (size_t)(NN * DOUT) + lane;
        #pragma unroll
        for (int n = 0; n < NN; ++n) {
            float s = adiag[n] * Mreg[n] * h0[n];
            #pragma unroll
            for (int m = 0; m < NN; ++m)
                s = fmaf(aoff[n][m], h1[m], s);
            orow[n*DOUT] = (s + bo) * 1e-9f;
        }
    }
}

extern "C" void kernel_launch(void* const* d_in, const int* in_sizes, int n_in,
                              void* d_out, int out_size, void* d_ws, size_t ws_size,
                              hipStream_t stream) {
    const float* x    = (const float*)d_in[0];
    const float* W    = (const float*)d_in[1];
    const float* M    = (const float*)d_in[2];
    const float* adj2 = (const float*)d_in[3];
    const float* bias = (const float*)d_in[4];
    const float* adj  = (const float*)d_in[5];
    float* out = (float*)d_out;

    const int nGroups    = NBT / GRP;   // 9600
    const int gridBlocks = 1920;        // 5 groups per block

    hipLaunchKernelGGL(gcn_fp32_kernel, dim3(gridBlocks), dim3(256), 0, stream,
                       x, W, M, adj2, bias, adj, out, nGroups, gridBlocks);
}

// Round 2
// 104.198 us; speedup vs baseline: 2.4919x; 2.4919x over previous
//
#include <hip/hip_runtime.h>
#include <hip/hip_bf16.h>

typedef float  f32x4  __attribute__((ext_vector_type(4)));
typedef short  bf16x8 __attribute__((ext_vector_type(8)));
typedef unsigned short ushort8v __attribute__((ext_vector_type(8)));

#define NN   17
#define GRP  4
#define ROWS (GRP*NN)       // 68
#define NBT  (128*300)
#define NCH  (NBT/GRP)      // 9600
#define GRID 1920
#define CPB  (NCH/GRID)     // 5

// ws layout (float indices): [0,544) aoff rows (stride 32), [544,561) adiag,
// [576...) Wt bf16 [128 cols][64 k] as ushort (8192 entries = 16KB)

__global__ void gcn_prep(const float* __restrict__ W,
                         const float* __restrict__ adj2,
                         const float* __restrict__ adj,
                         float* __restrict__ ws) {
    int t = threadIdx.x;
    for (int idx = t; idx < NN*NN; idx += 256) {
        int n = idx / NN, m = idx % NN;
        float v = 0.5f * ((adj[n*NN+m] + adj2[n*NN+m]) + (adj[m*NN+n] + adj2[m*NN+n]));
        ws[n*32 + m] = (n == m) ? 0.0f : v;
        if (n == m) ws[544 + n] = v;
    }
    unsigned short* wt = (unsigned short*)(ws + 576);
    for (int idx = t; idx < 128*64; idx += 256) {
        int c = idx >> 6, i = idx & 63;      // col c (0..127), k index i
        float f = W[(c >> 6)*4096 + i*64 + (c & 63)];
        wt[idx] = __builtin_bit_cast(unsigned short, __float2bfloat16(f));
    }
}

__device__ __forceinline__ void stage_unit(unsigned short* xs, int u, const float4* ld) {
    int row = u >> 2, q = u & 3;
    int sw = (row & 7) << 4;
    char* base = (char*)xs + row * 128;
    #pragma unroll
    for (int h = 0; h < 2; ++h) {
        ushort8v v;
        #pragma unroll
        for (int j2 = 0; j2 < 2; ++j2) {
            float4 f = ld[h*2 + j2];
            v[j2*4+0] = __builtin_bit_cast(unsigned short, __float2bfloat16(f.x));
            v[j2*4+1] = __builtin_bit_cast(unsigned short, __float2bfloat16(f.y));
            v[j2*4+2] = __builtin_bit_cast(unsigned short, __float2bfloat16(f.z));
            v[j2*4+3] = __builtin_bit_cast(unsigned short, __float2bfloat16(f.w));
        }
        *(ushort8v*)(base + ((q*32 + h*16) ^ sw)) = v;
    }
}

__global__ __launch_bounds__(256, 2) void gcn_main(
    const float* __restrict__ x, const float* __restrict__ M,
    const float* __restrict__ bias, const float* __restrict__ ws,
    float* __restrict__ out)
{
    __shared__ unsigned short xs[80*64];   // bf16 X, XOR-swizzled rows (128B/row)
    __shared__ float Ht[128*85];           // H^T [col][padded row p = bt*20+n]
    __shared__ float adMl[NN*68];          // adiag[n]*M[n][o]
    __shared__ float Ml[NN*68];            // M[n][o]

    const int tid  = threadIdx.x;
    const int lane = tid & 63;
    const int w    = tid >> 6;

    // tables
    for (int idx = tid; idx < NN*64; idx += 256) {
        int n = idx >> 6, o = idx & 63;
        float m = M[n*64 + o];
        float d = ws[544 + n];
        adMl[n*68 + o] = d * m;
        Ml[n*68 + o]   = m;
    }
    // zero unused X rows 68..79 (MFMA row-tile 4 reads them)
    for (int idx = tid; idx < 12*64; idx += 256) xs[68*64 + idx] = 0;

    // W B-fragments in registers: wave w owns global col-tiles 2w, 2w+1
    const unsigned short* wt = (const unsigned short*)(ws + 576);
    bf16x8 bfrag[2][2];
    #pragma unroll
    for (int ct = 0; ct < 2; ++ct) {
        int c = (2*w + ct)*16 + (lane & 15);
        #pragma unroll
        for (int ks = 0; ks < 2; ++ks)
            bfrag[ct][ks] = *(const bf16x8*)(wt + c*64 + ks*32 + (lane >> 4)*8);
    }
    const float bo = bias[lane];

    const bool extra = (tid >= 192 && tid < 208);   // wave 3 low lanes stage units 256..271
    const int  u1 = 256 + (tid - 192);

    float4 ld0[4], ld1[4];
    const int c0 = blockIdx.x;
    {
        const float4* src = (const float4*)(x + (size_t)c0 * ROWS * 64);
        #pragma unroll
        for (int j = 0; j < 4; ++j) ld0[j] = src[tid*4 + j];
        if (extra) {
            #pragma unroll
            for (int j = 0; j < 4; ++j) ld1[j] = src[u1*4 + j];
        }
    }

    for (int k = 0; k < CPB; ++k) {
        const int c = c0 + k*GRID;

        // --- A: cvt + swizzled ds_write of X chunk ---
        stage_unit(xs, tid, ld0);
        if (extra) stage_unit(xs, u1, ld1);
        __syncthreads();

        // T14: issue next chunk's global loads before compute
        if (k + 1 < CPB) {
            const float4* src = (const float4*)(x + (size_t)(c + GRID) * ROWS * 64);
            #pragma unroll
            for (int j = 0; j < 4; ++j) ld0[j] = src[tid*4 + j];
            if (extra) {
                #pragma unroll
                for (int j = 0; j < 4; ++j) ld1[j] = src[u1*4 + j];
            }
        }

        // --- B: MFMA. wave w computes all 5 row-tiles x its 2 col-tiles ---
        f32x4 acc[5][2];
        #pragma unroll
        for (int rt = 0; rt < 5; ++rt)
            #pragma unroll
            for (int ct = 0; ct < 2; ++ct)
                acc[rt][ct] = f32x4{0.f, 0.f, 0.f, 0.f};

        #pragma unroll
        for (int rt = 0; rt < 5; ++rt) {
            int row = rt*16 + (lane & 15);
            int sw  = (row & 7) << 4;
            const char* xb = (const char*)xs + row*128;
            bf16x8 a0 = *(const bf16x8*)(xb + (((lane >> 4)*16)      ^ sw));
            bf16x8 a1 = *(const bf16x8*)(xb + ((64 + (lane >> 4)*16) ^ sw));
            #pragma unroll
            for (int ct = 0; ct < 2; ++ct) {
                acc[rt][ct] = __builtin_amdgcn_mfma_f32_16x16x32_bf16(a0, bfrag[ct][0], acc[rt][ct], 0, 0, 0);
                acc[rt][ct] = __builtin_amdgcn_mfma_f32_16x16x32_bf16(a1, bfrag[ct][1], acc[rt][ct], 0, 0, 0);
            }
        }

        // --- C: scale by (diag*M | M) and write H^T to LDS ---
        #pragma unroll
        for (int rt = 0; rt < 5; ++rt) {
            #pragma unroll
            for (int ct = 0; ct < 2; ++ct) {
                int col = (2*w + ct)*16 + (lane & 15);
                int o   = col & 63;
                const float* tab = (col < 64) ? adMl : Ml;   // wave-uniform select
                #pragma unroll
                for (int r = 0; r < 4; ++r) {
                    int row = rt*16 + ((lane >> 4)*4) + r;
                    if (row < ROWS) {
                        int bt = (row * 241) >> 12;          // row/17 for row<80
                        int n  = row - bt*17;
                        Ht[col*85 + bt*20 + n] = tab[n*68 + o] * acc[rt][ct][r];
                    }
                }
            }
        }
        __syncthreads();

        // --- D: mixing. wave w -> bt-local w; lane = output col o ---
        float h1v[NN];
        {
            const float* h1p = &Ht[(64 + lane)*85 + w*20];
            #pragma unroll
            for (int m = 0; m < NN; ++m) h1v[m] = h1p[m];
        }
        const float* h0p = &Ht[lane*85 + w*20];
        size_t ob = ((size_t)(c*GRP + w) * NN) * 64 + lane;
        #pragma unroll 1
        for (int n = 0; n < NN; ++n) {
            const float* ar = ws + n*32;     // uniform -> s_load operands
            float s = h0p[n];
            #pragma unroll
            for (int m = 0; m < NN; ++m) s = fmaf(ar[m], h1v[m], s);
            out[ob + (size_t)n*64] = (s + bo) * 1e-9f;
        }
        __syncthreads();
    }
}

extern "C" void kernel_launch(void* const* d_in, const int* in_sizes, int n_in,
                              void* d_out, int out_size, void* d_ws, size_t ws_size,
                              hipStream_t stream) {
    const float* x    = (const float*)d_in[0];
    const float* W    = (const float*)d_in[1];
    const float* M    = (const float*)d_in[2];
    const float* adj2 = (const float*)d_in[3];
    const float* bias = (const float*)d_in[4];
    const float* adj  = (const float*)d_in[5];
    float* out = (float*)d_out;
    float* ws  = (float*)d_ws;

    hipLaunchKernelGGL(gcn_prep, dim3(1), dim3(256), 0, stream, W, adj2, adj, ws);
    hipLaunchKernelGGL(gcn_main, dim3(GRID), dim3(256), 0, stream, x, M, bias, ws, out);
}

// Round 3
// 86.821 us; speedup vs baseline: 2.9906x; 1.2001x over previous
//
#include <hip/hip_runtime.h>
#include <hip/hip_bf16.h>

typedef float  f32x4  __attribute__((ext_vector_type(4)));
typedef short  bf16x8 __attribute__((ext_vector_type(8)));
typedef unsigned short ushort8v __attribute__((ext_vector_type(8)));

#define NN   17
#define GRP  4
#define ROWS (GRP*NN)       // 68
#define NBT  (128*300)
#define NCH  (NBT/GRP)      // 9600
#define GRID 1920
#define CPB  (NCH/GRID)     // 5
#define HSTR 136            // Ht col stride in ushorts (272 B)

// ws layout (float indices): [0,544) aoff rows (stride 32), [544,561) adiag,
// [576...) Wt bf16 [128 cols][64 k] as ushort (8192 entries = 16KB)

__global__ void gcn_prep(const float* __restrict__ W,
                         const float* __restrict__ adj2,
                         const float* __restrict__ adj,
                         float* __restrict__ ws) {
    int t = threadIdx.x;
    for (int idx = t; idx < NN*NN; idx += 256) {
        int n = idx / NN, m = idx % NN;
        float v = 0.5f * ((adj[n*NN+m] + adj2[n*NN+m]) + (adj[m*NN+n] + adj2[m*NN+n]));
        ws[n*32 + m] = (n == m) ? 0.0f : v;
        if (n == m) ws[544 + n] = v;
    }
    unsigned short* wt = (unsigned short*)(ws + 576);
    for (int idx = t; idx < 128*64; idx += 256) {
        int c = idx >> 6, i = idx & 63;      // col c (0..127), k index i
        float f = W[(c >> 6)*4096 + i*64 + (c & 63)];
        wt[idx] = __builtin_bit_cast(unsigned short, __float2bfloat16(f));
    }
}

__device__ __forceinline__ float b2f(unsigned short u) {
    return __builtin_bit_cast(float, ((unsigned)u) << 16);
}

__device__ __forceinline__ void stage_unit(unsigned short* xs, int u, const float4* src) {
    int row = u >> 2, q = u & 3;
    int sw = (row & 7) << 4;
    char* base = (char*)xs + row * 128;
    float4 ld[4];
    #pragma unroll
    for (int j = 0; j < 4; ++j) ld[j] = src[u*4 + j];
    #pragma unroll
    for (int h = 0; h < 2; ++h) {
        ushort8v v;
        #pragma unroll
        for (int j2 = 0; j2 < 2; ++j2) {
            float4 f = ld[h*2 + j2];
            v[j2*4+0] = __builtin_bit_cast(unsigned short, __float2bfloat16(f.x));
            v[j2*4+1] = __builtin_bit_cast(unsigned short, __float2bfloat16(f.y));
            v[j2*4+2] = __builtin_bit_cast(unsigned short, __float2bfloat16(f.z));
            v[j2*4+3] = __builtin_bit_cast(unsigned short, __float2bfloat16(f.w));
        }
        *(ushort8v*)(base + ((q*32 + h*16) ^ sw)) = v;
    }
}

__global__ __launch_bounds__(256, 4) void gcn_main(
    const float* __restrict__ x, const float* __restrict__ M,
    const float* __restrict__ bias, const float* __restrict__ ws,
    float* __restrict__ out)
{
    __shared__ unsigned short xs[80*64];       // 10240 B, XOR-swizzled bf16 X
    __shared__ unsigned short Ht[ROWS*HSTR];   // 18496 B, bf16 H [row bt*17+n][col]

    const int tid  = threadIdx.x;
    const int lane = tid & 63;
    const int w    = tid >> 6;

    // Per-lane M columns + bias in registers (o = lane)
    float Mreg[NN];
    #pragma unroll
    for (int n = 0; n < NN; ++n) Mreg[n] = M[n*64 + lane];
    const float bo = bias[lane];

    // W B-fragments in registers: wave w owns global col-tiles 2w, 2w+1
    const unsigned short* wt = (const unsigned short*)(ws + 576);
    bf16x8 bfrag[2][2];
    #pragma unroll
    for (int ct = 0; ct < 2; ++ct) {
        int c = (2*w + ct)*16 + (lane & 15);
        #pragma unroll
        for (int ks = 0; ks < 2; ++ks)
            bfrag[ct][ks] = *(const bf16x8*)(wt + c*64 + ks*32 + (lane >> 4)*8);
    }

    // zero unused X rows 68..79 (MFMA row-tile 4 reads them)
    for (int idx = tid; idx < 12*64; idx += 256) xs[68*64 + idx] = 0;

    const bool extra = (tid >= 192 && tid < 208);   // wave 3 low lanes stage units 256..271
    const int  u1 = 256 + (tid - 192);

    for (int k = 0; k < CPB; ++k) {
        const int c = blockIdx.x + k*GRID;

        // --- A: global load -> cvt -> swizzled ds_write ---
        const float4* src = (const float4*)(x + (size_t)c * ROWS * 64);
        stage_unit(xs, tid, src);
        if (extra) stage_unit(xs, u1, src);
        __syncthreads();   // bar1: xs ready; also all threads done with prev D (Ht free)

        // --- B: MFMA. wave w computes 5 row-tiles x its 2 col-tiles ---
        f32x4 acc[5][2];
        #pragma unroll
        for (int rt = 0; rt < 5; ++rt)
            #pragma unroll
            for (int ct = 0; ct < 2; ++ct)
                acc[rt][ct] = f32x4{0.f, 0.f, 0.f, 0.f};

        #pragma unroll
        for (int rt = 0; rt < 5; ++rt) {
            int row = rt*16 + (lane & 15);
            int sw  = (row & 7) << 4;
            const char* xb = (const char*)xs + row*128;
            bf16x8 a0 = *(const bf16x8*)(xb + (((lane >> 4)*16)      ^ sw));
            bf16x8 a1 = *(const bf16x8*)(xb + ((64 + (lane >> 4)*16) ^ sw));
            #pragma unroll
            for (int ct = 0; ct < 2; ++ct) {
                acc[rt][ct] = __builtin_amdgcn_mfma_f32_16x16x32_bf16(a0, bfrag[ct][0], acc[rt][ct], 0, 0, 0);
                acc[rt][ct] = __builtin_amdgcn_mfma_f32_16x16x32_bf16(a1, bfrag[ct][1], acc[rt][ct], 0, 0, 0);
            }
        }

        // --- C: write raw H as bf16 to Ht[row][col] ---
        #pragma unroll
        for (int rt = 0; rt < 5; ++rt) {
            #pragma unroll
            for (int ct = 0; ct < 2; ++ct) {
                int col = (2*w + ct)*16 + (lane & 15);
                #pragma unroll
                for (int r = 0; r < 4; ++r) {
                    int row = rt*16 + ((lane >> 4)*4) + r;
                    if (row < ROWS)
                        Ht[row*HSTR + col] =
                            __builtin_bit_cast(unsigned short, __float2bfloat16(acc[rt][ct][r]));
                }
            }
        }
        __syncthreads();   // bar2: Ht ready

        // --- D: mixing. wave w -> bt-local w; lane = output col o ---
        const unsigned short* h0p = &Ht[(w*NN)*HSTR + lane];
        const unsigned short* h1p = h0p + 64;
        float h1v[NN];
        #pragma unroll
        for (int m = 0; m < NN; ++m) h1v[m] = b2f(h1p[m*HSTR]) * Mreg[m];

        size_t ob = ((size_t)(c*GRP + w) * NN) * 64 + lane;
        #pragma unroll 1
        for (int n = 0; n < NN; ++n) {
            const float* ar = ws + n*32;              // uniform -> s_load operands
            float s = (ws[544 + n] * Mreg[n]) * b2f(h0p[n*HSTR]);  // diag term
            #pragma unroll
            for (int m = 0; m < NN; ++m) s = fmaf(ar[m], h1v[m], s);
            out[ob + (size_t)n*64] = (s + bo) * 1e-9f;
        }
        // no trailing barrier: next bar1 protects xs/Ht reuse
    }
}

extern "C" void kernel_launch(void* const* d_in, const int* in_sizes, int n_in,
                              void* d_out, int out_size, void* d_ws, size_t ws_size,
                              hipStream_t stream) {
    const float* x    = (const float*)d_in[0];
    const float* W    = (const float*)d_in[1];
    const float* M    = (const float*)d_in[2];
    const float* adj2 = (const float*)d_in[3];
    const float* bias = (const float*)d_in[4];
    const float* adj  = (const float*)d_in[5];
    float* out = (float*)d_out;
    float* ws  = (float*)d_ws;

    hipLaunchKernelGGL(gcn_prep, dim3(1), dim3(256), 0, stream, W, adj2, adj, ws);
    hipLaunchKernelGGL(gcn_main, dim3(GRID), dim3(256), 0, stream, x, M, bias, ws, out);
}